// Round 11
// baseline (216.290 us; speedup 1.0000x reference)
//
#include <hip/hip_runtime.h>
#include <hip/hip_fp16.h>
#include <math.h>
#include <type_traits>

// ----------------------------------------------------------------------------
// NL-means denoise (skimage slow-mode math) + db2-wavelet sigma estimate.
// R22: SPLIT-PAIRING (conflict-free strides) replacing R20/R21's adjacent
//   pairing. R21b post-mortem: adjacent-col remap cut LDS instrs but pushed
//   all phase-C accesses to 16B/lane stride -> conflicts 4.68M->10.33M
//   (~12% of cycles), net 0. Mechanism now confirmed twice (R20 phase A
//   did the same). Fix: pair SPLIT elements so lane stride stays <=8B:
//   - C: cols (c, c+32), rows (rg2, rg2+1), c=tid&31. swt b32 @4B/lane,
//     spx b64 @8B/lane -> conflict-free; col/row pairs are ds_read2
//     merge candidates (delta 128/256/304/736B). Cell body = R19 verbatim.
//   - A: sds cols (j, j+40) per row; reads 4x b64 @8B stride (read2 pairs
//     delta 320B), writes 2x b32 @4B stride (write2 pair delta 160B).
//   - W: col-pairs (2q,2q+1)+(2q+38,2q+39); b64 @8B stride (read2 delta
//     152B) replacing 16B-stride b128 quad.
//   All arithmetic BIT-IDENTICAL (same sds/shh/swt layouts, same chains).
// R19 kept: 64x64 tile, 1024 thr, 1 block/CU (halo amortization).
// R15 kept: phase C via v_dot2_f32_f16 + v_perm packing.
// R13 kept: swt own buffer -> 3 barriers/iter, C overlaps next A.
// Prologue = R13 3-kernel launch (~4us; ~60us bench-kernel gap is fixed
//   harness overhead). Spill tripwire: WRITE_SIZE must stay ~12.3MB.
// ----------------------------------------------------------------------------

#define IMG   1024
#define HH_S  257
#define NBINS 4096
#define NREP  2
#define BIN_SCALE 4096.0f
#define MED_K 33025      // n=257*257=66049 odd: median = a[33024] (0-based)

#define TW 64
#define TH 64
#define NT 1024                      // threads per block
// spx: rows -8..71 (80) x cols -14..77 (92)
#define PROWS 80
#define PCOLS 92
#define NPIX (PROWS*PCOLS)           // 7360
#define PXB(r,c) (((r)+8)*PCOLS + ((c)+14))
// sds: rows -8..65 (74) x cols -8..71 (80)
#define DROWS 74
#define DCOLS 80
#define ND (DROWS*DCOLS)             // 5920
#define NPAIR (ND/2)                 // 2960 split-pair A tasks (40/row)
#define NPTAIL (NPAIR - 2*NT)        // 912: k=2 partial
// shh: rows -8..65 (74) x cols -6..69 (76)
#define HCOLS 76
#define NB (DROWS*19)                // 1406 horiz-conv b128 tasks
// swt: rows -6..63 (70) x cols -6..69 (76)
#define WROWS 70
#define NWQ (WROWS*19)               // 1330 W tasks (2 col-pairs each)
#define SWB(r,c) (((r)+6)*HCOLS + ((c)+6))

// Gaussian patch kernel, normalized separable taps
#define G0 0.05448868454910367f
#define G1 0.24420134203151178f
#define G2 0.40261994689466440f
// horizontal pass taps pre-multiplied by 1/3 (channel mean)
#define B0 0.01816289484970122f
#define B1 0.08140044734383726f
#define B2 0.13420664896488813f

#define MAD_INV 1.4826022185056018f
#define LOG2E   1.4426950408889634f

typedef _Float16 half2v __attribute__((ext_vector_type(2)));
union PxU { uint2 u; half2v h[2]; };
union Q4  { uint4 u; half2v h[4]; };
union Q2  { uint2 u; half2v h[2]; };
#define H2(x) half2v{(_Float16)(x), (_Float16)(x)}

// ---------------------------------------------------------------- helpers
__device__ __forceinline__ float diff2(half2v a01, half2v a2, half2v b01, half2v b2) {
#if __has_builtin(__builtin_amdgcn_fdot2)
    half2v e01 = a01 - b01;
    half2v e2  = a2  - b2;
    return __builtin_amdgcn_fdot2(e01, e01,
           __builtin_amdgcn_fdot2(e2, e2, 0.f, false), false);
#else
    float e0 = (float)a01[0] - (float)b01[0];
    float e1 = (float)a01[1] - (float)b01[1];
    float e2 = (float)a2[0]  - (float)b2[0];
    return e0 * e0 + e1 * e1 + e2 * e2;
#endif
}

__device__ __forceinline__ float dot2(half2v a, half2v b, float c) {
#if __has_builtin(__builtin_amdgcn_fdot2)
    return __builtin_amdgcn_fdot2(a, b, c, false);
#else
    return c + (float)a[0] * (float)b[0] + (float)a[1] * (float)b[1];
#endif
}

__device__ __forceinline__ half2v pack2(float a, float b) {
#if __has_builtin(__builtin_amdgcn_cvt_pkrtz)
    return __builtin_bit_cast(half2v, __builtin_amdgcn_cvt_pkrtz(a, b));
#else
    return half2v{(_Float16)a, (_Float16)b};
#endif
}

// pack (lo16(A), lo16(B)) / (hi16(A), hi16(B)) / (lo16(A), hi16(B)) as half2
__device__ __forceinline__ half2v pklo(unsigned A, unsigned B) {
#if __has_builtin(__builtin_amdgcn_perm)
    return __builtin_bit_cast(half2v, __builtin_amdgcn_perm(B, A, 0x05040100u));
#else
    return __builtin_bit_cast(half2v, (A & 0xffffu) | (B << 16));
#endif
}
__device__ __forceinline__ half2v pkhi(unsigned A, unsigned B) {
#if __has_builtin(__builtin_amdgcn_perm)
    return __builtin_bit_cast(half2v, __builtin_amdgcn_perm(B, A, 0x07060302u));
#else
    return __builtin_bit_cast(half2v, (A >> 16) | (B & 0xffff0000u));
#endif
}
__device__ __forceinline__ half2v pklh(unsigned A, unsigned B) {
#if __has_builtin(__builtin_amdgcn_perm)
    return __builtin_bit_cast(half2v, __builtin_amdgcn_perm(B, A, 0x07060100u));
#else
    return __builtin_bit_cast(half2v, (A & 0xffffu) | (B & 0xffff0000u));
#endif
}

// load reflect-padded pixel tile, pack RGB -> 3xfp16 in uint2
__device__ __forceinline__ void tile_load(const float* __restrict__ x, uint2* spx,
                                          int tid, int X0, int Y0) {
    for (int l = tid; l < NPIX; l += NT) {
        int rr = l / PCOLS;
        int cc = l - rr * PCOLS;
        int sy = Y0 + rr - 8;
        sy = sy < 0 ? -sy : (sy >= IMG ? 2 * IMG - 2 - sy : sy);
        int sc = X0 + cc - 14;
        sc = sc < 0 ? -sc : (sc >= IMG ? 2 * IMG - 2 - sc : sc);
        const float* p = x + ((size_t)sy * IMG + sc) * 3;
        uint2 u;
        u.x = (unsigned)__half_as_ushort(__float2half_rn(p[0])) |
              ((unsigned)__half_as_ushort(__float2half_rn(p[1])) << 16);
        u.y = (unsigned)__half_as_ushort(__float2half_rn(p[2]));  // hi 16 = 0
        spx[l] = u;
    }
}

// ---------------------------------------------------------------- stage 1
// (verbatim R13 -- measured ~2-3us)
__global__ void wavelet_hist(const float* __restrict__ x, int* __restrict__ hist) {
    int idx = blockIdx.x * 256 + threadIdx.x;
    if (idx >= HH_S * HH_S) return;
    int* hrep = hist + (blockIdx.x & (NREP - 1)) * 3 * NBINS;
    int i = (idx / HH_S) * 2;
    int j = (idx - (idx / HH_S) * HH_S) * 2;
    const float k4[4] = {-0.48296291314469025f, 0.8365163037378079f,
                         -0.2241438680420134f, -0.12940952255126037f};
    float acc0 = 0.f, acc1 = 0.f, acc2 = 0.f;
    const bool fast = (j >= 2 && j <= 511);
#pragma unroll
    for (int a = 0; a < 4; ++a) {
        int sy = 2 * i + a - 3;                       // 'symmetric' pad
        sy = sy < 0 ? -sy - 1 : (sy >= IMG ? 2 * IMG - 1 - sy : sy);
        const float* row = x + (size_t)sy * IMG * 3;
        float r0, r1, r2;
        if (fast) {
            const float* p = row + (2 * j - 3) * 3;
            float f0 = p[0], f1 = p[1], f2 = p[2], f3 = p[3];
            float f4 = p[4], f5 = p[5], f6 = p[6], f7 = p[7];
            float f8 = p[8], f9 = p[9], f10 = p[10], f11 = p[11];
            r0 = k4[0] * f0 + k4[1] * f3 + k4[2] * f6 + k4[3] * f9;
            r1 = k4[0] * f1 + k4[1] * f4 + k4[2] * f7 + k4[3] * f10;
            r2 = k4[0] * f2 + k4[1] * f5 + k4[2] * f8 + k4[3] * f11;
        } else {
            r0 = r1 = r2 = 0.f;
#pragma unroll
            for (int b = 0; b < 4; ++b) {
                int sx = 2 * j + b - 3;
                sx = sx < 0 ? -sx - 1 : (sx >= IMG ? 2 * IMG - 1 - sx : sx);
                const float* p = row + sx * 3;
                r0 += k4[b] * p[0]; r1 += k4[b] * p[1]; r2 += k4[b] * p[2];
            }
        }
        acc0 += k4[a] * r0; acc1 += k4[a] * r1; acc2 += k4[a] * r2;
    }
    int b0 = (int)(fabsf(acc0) * BIN_SCALE); b0 = b0 > NBINS - 1 ? NBINS - 1 : b0;
    int b1 = (int)(fabsf(acc1) * BIN_SCALE); b1 = b1 > NBINS - 1 ? NBINS - 1 : b1;
    int b2 = (int)(fabsf(acc2) * BIN_SCALE); b2 = b2 > NBINS - 1 ? NBINS - 1 : b2;
    atomicAdd(&hrep[b0], 1);
    atomicAdd(&hrep[NBINS + b1], 1);
    atomicAdd(&hrep[2 * NBINS + b2], 1);
}

// ---------------------------------------------------------------- stage 2
// (verbatim R13 -- one block per channel; accumulates med*MAD_INV/3 into scal[0])
__global__ void sigma_scan(const int* __restrict__ hist, float* __restrict__ scal) {
    __shared__ int   wsum[16];
    __shared__ float sres[1];
    const int t = threadIdx.x;
    const int lane = t & 63, wid = t >> 6;
    const int c = blockIdx.x;
    const int* h = hist + c * NBINS;
    int cnt[4]; int tsum = 0;
#pragma unroll
    for (int b = 0; b < 4; ++b) {
        int bin = t * 4 + b, s = 0;
#pragma unroll
        for (int r = 0; r < NREP; ++r) s += h[r * 3 * NBINS + bin];
        cnt[b] = s; tsum += s;
    }
    int incl = tsum;
#pragma unroll
    for (int o = 1; o < 64; o <<= 1) {
        int v = __shfl_up(incl, o);
        if (lane >= o) incl += v;
    }
    if (lane == 63) wsum[wid] = incl;
    __syncthreads();
    if (wid == 0) {
        int v = (lane < 16) ? wsum[lane] : 0;
        int inc = v;
#pragma unroll
        for (int o = 1; o < 16; o <<= 1) {
            int u = __shfl_up(inc, o);
            if (lane >= o) inc += u;
        }
        if (lane < 16) wsum[lane] = inc - v;
    }
    __syncthreads();
    int cum = wsum[wid] + incl - tsum;
#pragma unroll
    for (int b = 0; b < 4; ++b) {
        int nc = cum + cnt[b];
        float v = (t * 4 + b + 0.5f) * (1.0f / BIN_SCALE);
        if (cum < MED_K && nc >= MED_K) sres[0] = v;
        cum = nc;
    }
    __syncthreads();
    if (t == 0) atomicAdd(&scal[0], sres[0] * (MAD_INV / 3.0f));
}

// ---------------------------------------------------------------- main loop
// 42 iters x (A: split-pair diff^2 -> sds, B: horiz 5-tap -> shh,
// W: split col-pair vert 5-tap + exp2 -> swt, C: 2x2 split fdot2). 3 barriers.
__device__ __forceinline__ void nlm_loop(float* __restrict__ out, float sigma,
                                         uint2* spx, half2v* sds, half2v* shh,
                                         half2v* swt, int tid, int X0, int Y0) {
    const float var   = 2.0f * sigma * sigma;
    const float ih2l  = LOG2E / (0.64f * sigma * sigma);   // h = 0.8*sigma

    const int cbase = tid & 31;       // cols cbase, cbase+32
    const int rg2   = (tid >> 5) * 2; // rows rg2, rg2+1
    // acc index = 2*ri + ci  (ri=row 0/1, ci=col 0->c, 1->c+32)
    float accx[4] = {0, 0, 0, 0}, accy[4] = {0, 0, 0, 0};
    float accz[4] = {0, 0, 0, 0}, accw[4] = {0, 0, 0, 0};

    __syncthreads();

    // --- register-cache center values for split-pair phase A tasks:
    // task pr: row dr = pr/40, slot j = pr-40*dr; covers sds cols j and j+40.
    half2v cA01[3], cA2[3], cB01[3], cB2[3];
    int    pba[3], sbw[3];
#pragma unroll
    for (int k = 0; k < 3; ++k) {
        int pr = (k < 2 || tid < NPTAIL) ? tid + k * NT : 0;
        int dr = pr / 40;
        int j  = pr - dr * 40;
        pba[k] = dr * PCOLS + j + 6;   // PXB(dr-8, j-8)
        sbw[k] = dr * DCOLS + j;
        PxU a; a.u = spx[pba[k]];
        PxU b; b.u = spx[pba[k] + 40];
        cA01[k] = a.h[0]; cA2[k] = a.h[1];
        cB01[k] = b.h[0]; cB2[k] = b.h[1];
    }

    const half2v B0h = H2(B0), B1h = H2(B1), B2h = H2(B2);
    const half2v G0h = H2(G0), G1h = H2(G1), G2h = H2(G2);
    const half2v ones = H2(1.0f);

    // ---- pair body: offsets o1=(oy1,ox1), o2=(oy2,ox2) packed as half2;
    // each serves BOTH +o and -o directions (dist_{-o}(p) = dist_o(p-o)).
    auto pair_body = [&](auto mtag, int oy1, int ox1, int oy2, int ox2) {
        constexpr bool MERGED = decltype(mtag)::value;
        const int d1off = oy1 * PCOLS + ox1;
        const int d2off = oy2 * PCOLS + ox2;

        // -------- phase A: split-pair diff^2 -> sds; reads b64 @8B stride
        // (read2 candidates, delta 320B), writes b32 @4B stride (write2 160B)
#pragma unroll
        for (int k = 0; k < 3; ++k) {
            if (k < 2 || tid < NPTAIL) {
                PxU p0, p1, p2, p3;
                p0.u = spx[pba[k] + d1off];
                p2.u = spx[pba[k] + 40 + d1off];
                if constexpr (MERGED) {
                    p1.u = spx[pba[k] + d1off + 1];
                    p3.u = spx[pba[k] + 41 + d1off];
                } else {
                    p1.u = spx[pba[k] + d2off];
                    p3.u = spx[pba[k] + 40 + d2off];
                }
                float da0 = diff2(cA01[k], cA2[k], p0.h[0], p0.h[1]);
                float db0 = diff2(cA01[k], cA2[k], p1.h[0], p1.h[1]);
                float da1 = diff2(cB01[k], cB2[k], p2.h[0], p2.h[1]);
                float db1 = diff2(cB01[k], cB2[k], p3.h[0], p3.h[1]);
                sds[sbw[k]]      = pack2(da0, db0);
                sds[sbw[k] + 40] = pack2(da1, db1);
            }
        }
        __syncthreads();

        // -------- phase B: packed horizontal conv -> shh (1406 b128 tasks)
        {
            int row = tid / 19, g = tid - row * 19;
            int b = row * DCOLS + 4 * g;
            Q4 a, q, o;
            a.u = *(const uint4*)&sds[b];
            q.u = *(const uint4*)&sds[b + 4];
            o.h[0] = B0h * a.h[0] + B1h * a.h[1] + B2h * a.h[2] + B1h * a.h[3] + B0h * q.h[0];
            o.h[1] = B0h * a.h[1] + B1h * a.h[2] + B2h * a.h[3] + B1h * q.h[0] + B0h * q.h[1];
            o.h[2] = B0h * a.h[2] + B1h * a.h[3] + B2h * q.h[0] + B1h * q.h[1] + B0h * q.h[2];
            o.h[3] = B0h * a.h[3] + B1h * q.h[0] + B2h * q.h[1] + B1h * q.h[2] + B0h * q.h[3];
            *(uint4*)&shh[row * HCOLS + 4 * g] = o.u;
            if (tid < NB - NT) {
                int j2 = tid + NT;
                int row2 = j2 / 19, g2 = j2 - row2 * 19;
                int b2 = row2 * DCOLS + 4 * g2;
                a.u = *(const uint4*)&sds[b2];
                q.u = *(const uint4*)&sds[b2 + 4];
                o.h[0] = B0h * a.h[0] + B1h * a.h[1] + B2h * a.h[2] + B1h * a.h[3] + B0h * q.h[0];
                o.h[1] = B0h * a.h[1] + B1h * a.h[2] + B2h * a.h[3] + B1h * q.h[0] + B0h * q.h[1];
                o.h[2] = B0h * a.h[2] + B1h * a.h[3] + B2h * q.h[0] + B1h * q.h[1] + B0h * q.h[2];
                o.h[3] = B0h * a.h[3] + B1h * q.h[0] + B2h * q.h[1] + B1h * q.h[2] + B0h * q.h[3];
                *(uint4*)&shh[row2 * HCOLS + 4 * g2] = o.u;
            }
        }
        __syncthreads();

        // -------- phase W: vert conv + exp2, TWO split col-pairs per task
        // (m0 and m0+38); b64 @8B stride, read2/write2 candidates (152B)
#pragma unroll
        for (int k = 0; k < 2; ++k) {
            int t = tid + k * NT;
            if (k < 1 || t < NWQ) {
                int row = t / 19, q = t - row * 19;
                int m0 = row * HCOLS + 2 * q;
                int m1 = m0 + 38;
                Q2 s0, s1, s2, s3, s4, oA;
                Q2 t0, t1, t2, t3, t4, oB;
                s0.u = *(const uint2*)&shh[m0];
                t0.u = *(const uint2*)&shh[m1];
                s1.u = *(const uint2*)&shh[m0 + HCOLS];
                t1.u = *(const uint2*)&shh[m1 + HCOLS];
                s2.u = *(const uint2*)&shh[m0 + 2 * HCOLS];
                t2.u = *(const uint2*)&shh[m1 + 2 * HCOLS];
                s3.u = *(const uint2*)&shh[m0 + 3 * HCOLS];
                t3.u = *(const uint2*)&shh[m1 + 3 * HCOLS];
                s4.u = *(const uint2*)&shh[m0 + 4 * HCOLS];
                t4.u = *(const uint2*)&shh[m1 + 4 * HCOLS];
#pragma unroll
                for (int h = 0; h < 2; ++h) {
                    half2v dA = G0h * s0.h[h] + G1h * s1.h[h] + G2h * s2.h[h]
                              + G1h * s3.h[h] + G0h * s4.h[h];
                    half2v dB = G0h * t0.h[h] + G1h * t1.h[h] + G2h * t2.h[h]
                              + G1h * t3.h[h] + G0h * t4.h[h];
                    oA.h[h] = pack2(exp2f(fminf(var - (float)dA[0], 0.f) * ih2l),
                                    exp2f(fminf(var - (float)dA[1], 0.f) * ih2l));
                    oB.h[h] = pack2(exp2f(fminf(var - (float)dB[0], 0.f) * ih2l),
                                    exp2f(fminf(var - (float)dB[1], 0.f) * ih2l));
                }
                *(uint2*)&swt[m0] = oA.u;
                *(uint2*)&swt[m1] = oB.u;
            }
        }
        __syncthreads();

        // -------- phase C: 2 rows x 2 SPLIT cols (c, c+32) per thread;
        // swt b32 @4B/lane, spx b64 @8B/lane -> conflict-free; row/col
        // pairs are read2 merge candidates. Cell body = R19 verbatim.
        // (overlaps with next iteration's phase A — no trailing barrier)
#pragma unroll
        for (int ri = 0; ri < 2; ++ri) {
            const int r = rg2 + ri;
#pragma unroll
            for (int ci = 0; ci < 2; ++ci) {
                const int cc = cbase + 32 * ci;
                const int ai = 2 * ri + ci;
                half2v wp = swt[SWB(r, cc)];
                half2v fm;
                PxU pa, pbx, pm1, pm2;
                if constexpr (MERGED) {
                    int wmb = SWB(r - oy1, cc - ox1);
                    unsigned u1 = *(const unsigned*)&swt[wmb];
                    unsigned u2 = *(const unsigned*)&swt[wmb - 1];
                    fm = pklh(u1, u2);
                    int ab = PXB(r + oy1, cc + ox1);
                    pa.u  = spx[ab]; pbx.u = spx[ab + 1];
                    int mb = PXB(r - oy1, cc - ox1);
                    pm1.u = spx[mb]; pm2.u = spx[mb - 1];
                } else {
                    unsigned u1 = *(const unsigned*)&swt[SWB(r - oy1, cc - ox1)];
                    unsigned u2 = *(const unsigned*)&swt[SWB(r - oy2, cc - ox2)];
                    fm = pklh(u1, u2);
                    pa.u  = spx[PXB(r + oy1, cc + ox1)];
                    pbx.u = spx[PXB(r + oy2, cc + ox2)];
                    pm1.u = spx[PXB(r - oy1, cc - ox1)];
                    pm2.u = spx[PXB(r - oy2, cc - ox2)];
                }
                accx[ai] = dot2(fm, pklo(pm1.u.x, pm2.u.x),
                           dot2(wp, pklo(pa.u.x, pbx.u.x), accx[ai]));
                accy[ai] = dot2(fm, pkhi(pm1.u.x, pm2.u.x),
                           dot2(wp, pkhi(pa.u.x, pbx.u.x), accy[ai]));
                accz[ai] = dot2(fm, pklo(pm1.u.y, pm2.u.y),
                           dot2(wp, pklo(pa.u.y, pbx.u.y), accz[ai]));
                accw[ai] = dot2(fm, ones, dot2(wp, ones, accw[ai]));
            }
        }
    };

    // ---- 42 iterations cover 84 representative offsets x 2 directions:
    // oy=0: ox 1..6 as merged pairs (1,2),(3,4),(5,6)
#pragma unroll 1
    for (int pi = 0; pi < 3; ++pi)
        pair_body(std::integral_constant<bool, true>{}, 0, 1 + 2 * pi, 0, 2 + 2 * pi);
    // oy=1..6: ox -6..5 as 6 merged pairs per row
#pragma unroll 1
    for (int oy = 1; oy <= 6; ++oy)
#pragma unroll 1
        for (int pi = 0; pi < 6; ++pi)
            pair_body(std::integral_constant<bool, true>{}, oy, -6 + 2 * pi, oy, -5 + 2 * pi);
    // leftovers (oy,6) for oy=1..6 as 3 generic pairs
#pragma unroll 1
    for (int p = 0; p < 3; ++p)
        pair_body(std::integral_constant<bool, false>{}, 2 * p + 1, 6, 2 * p + 2, 6);

    // -------- offset (0,0): d=0 -> w=1
#pragma unroll
    for (int ri = 0; ri < 2; ++ri)
#pragma unroll
        for (int ci = 0; ci < 2; ++ci) {
            PxU p; p.u = spx[PXB(rg2 + ri, cbase + 32 * ci)];
            int ai = 2 * ri + ci;
            accx[ai] += (float)p.h[0][0];
            accy[ai] += (float)p.h[0][1];
            accz[ai] += (float)p.h[1][0];
            accw[ai] += 1.f;
        }

    // -------- epilogue
#pragma unroll
    for (int ri = 0; ri < 2; ++ri)
#pragma unroll
        for (int ci = 0; ci < 2; ++ci) {
            int ai = 2 * ri + ci;
            int po = ((Y0 + rg2 + ri) * IMG + X0 + cbase + 32 * ci) * 3;
            float rw = 1.f / accw[ai];
            out[po + 0] = accx[ai] * rw;
            out[po + 1] = accy[ai] * rw;
            out[po + 2] = accz[ai] * rw;
        }
}

// ---------------------------------------------------------------- stage 3
__launch_bounds__(NT, 4)
__global__ void nlm_main(const float* __restrict__ x,
                         const float* __restrict__ scal,
                         float* __restrict__ out) {
    __shared__ __align__(16) uint2  spx[NPIX];   // packed half RGB (RO in loop)
    __shared__ __align__(16) half2v sds[ND];     // diff^2 pairs
    __shared__ __align__(16) half2v shh[DROWS*HCOLS];  // horiz-conv pairs
    __shared__ __align__(16) half2v swt[WROWS*HCOLS];  // weight pairs

    const int tid = threadIdx.x;
    const int X0 = blockIdx.x * TW;
    const int Y0 = blockIdx.y * TH;

    tile_load(x, spx, tid, X0, Y0);
    const float sigma = scal[0];
    nlm_loop(out, sigma, spx, sds, shh, swt, tid, X0, Y0);
}

// ---------------------------------------------------------------- launch
extern "C" void kernel_launch(void* const* d_in, const int* in_sizes, int n_in,
                              void* d_out, int out_size, void* d_ws, size_t ws_size,
                              hipStream_t stream) {
    const float* x = (const float*)d_in[0];
    float* out = (float*)d_out;
    float* scal = (float*)d_ws;                       // [0] = sigma accumulator
    int* hist = (int*)((char*)d_ws + 64);             // NREP x 3 x 4096 ints

    // zero scal (sigma accum) + histograms in one memset
    (void)hipMemsetAsync(d_ws, 0, 64 + NREP * 3 * NBINS * sizeof(int), stream);
    wavelet_hist<<<(HH_S * HH_S + 255) / 256, 256, 0, stream>>>(x, hist);
    sigma_scan<<<3, 1024, 0, stream>>>(hist, scal);
    dim3 grid(IMG / TW, IMG / TH);                    // 16 x 16 = 256 = #CUs
    nlm_main<<<grid, NT, 0, stream>>>(x, scal, out);
}

// Round 12
// 212.312 us; speedup vs baseline: 1.0187x; 1.0187x over previous
//
#include <hip/hip_runtime.h>
#include <hip/hip_fp16.h>
#include <math.h>
#include <type_traits>

// ----------------------------------------------------------------------------
// NL-means denoise (skimage slow-mode math) + db2-wavelet sigma estimate.
// R23: R20 + SPLIT-PAIR PHASE A ONLY (single-variable change from the best
//   verified kernel). R22 post-mortem: changing A+W+C at once regressed
//   (151us, 13.1M conflicts); the culprit was W -- replacing the contiguous
//   b128 quad (16B/lane sequential = conflict-free GEMM pattern) with
//   16B/lane-stride b64 pairs (THE conflict pattern). Distilled bank rule:
//   contiguous <=8B/lane b32/b64 free; contiguous 16B/lane b128 free;
//   16B/lane-stride b64 = 4-way aliasing. R20's only remaining instance of
//   the bad pattern is phase A's adjacent-pair reads -> replace with split
//   cols (j, j+40): reads contiguous b64 @8B/lane, writes 2x b32 @4B/lane.
//   W stays R20's quad b128; C stays R19's 1x4 (<=8B/lane). A-variant
//   correctness covered by R22's passing run (absmax 0.0078125).
// R20 kept: W quad-width b128. R19 kept: 64x64 tile, 1024 thr, 1 block/CU,
//   C 1x4. R15 kept: phase C fdot2+perm. R13 kept: swt own buffer, 3
//   barriers/iter. Prologue = R13 3-kernel launch (~4us; ~60us bench-kernel
//   gap is fixed harness overhead). Spill tripwire: WRITE_SIZE ~12.3MB.
// ----------------------------------------------------------------------------

#define IMG   1024
#define HH_S  257
#define NBINS 4096
#define NREP  2
#define BIN_SCALE 4096.0f
#define MED_K 33025      // n=257*257=66049 odd: median = a[33024] (0-based)

#define TW 64
#define TH 64
#define NT 1024                      // threads per block
// spx: rows -8..71 (80) x cols -14..77 (92)
#define PROWS 80
#define PCOLS 92
#define NPIX (PROWS*PCOLS)           // 7360
#define PXB(r,c) (((r)+8)*PCOLS + ((c)+14))
// sds: rows -8..65 (74) x cols -8..71 (80)
#define DROWS 74
#define DCOLS 80
#define ND (DROWS*DCOLS)             // 5920
#define NPAIR (ND/2)                 // 2960 split-pair A tasks (40/row)
#define NPTAIL (NPAIR - 2*NT)        // 912: k=2 partial
// shh: rows -8..65 (74) x cols -6..69 (76)
#define HCOLS 76
#define NB (DROWS*19)                // 1406 horiz-conv b128 tasks
// swt: rows -6..63 (70) x cols -6..69 (76)
#define WROWS 70
#define NWQ (WROWS*19)               // 1330 col-quad W tasks
#define SWB(r,c) (((r)+6)*HCOLS + ((c)+6))

// Gaussian patch kernel, normalized separable taps
#define G0 0.05448868454910367f
#define G1 0.24420134203151178f
#define G2 0.40261994689466440f
// horizontal pass taps pre-multiplied by 1/3 (channel mean)
#define B0 0.01816289484970122f
#define B1 0.08140044734383726f
#define B2 0.13420664896488813f

#define MAD_INV 1.4826022185056018f
#define LOG2E   1.4426950408889634f

typedef _Float16 half2v __attribute__((ext_vector_type(2)));
union PxU { uint2 u; half2v h[2]; };
union Q4  { uint4 u; half2v h[4]; };
union Q2  { uint2 u; half2v h[2]; };
#define H2(x) half2v{(_Float16)(x), (_Float16)(x)}

// ---------------------------------------------------------------- helpers
__device__ __forceinline__ float diff2(half2v a01, half2v a2, half2v b01, half2v b2) {
#if __has_builtin(__builtin_amdgcn_fdot2)
    half2v e01 = a01 - b01;
    half2v e2  = a2  - b2;
    return __builtin_amdgcn_fdot2(e01, e01,
           __builtin_amdgcn_fdot2(e2, e2, 0.f, false), false);
#else
    float e0 = (float)a01[0] - (float)b01[0];
    float e1 = (float)a01[1] - (float)b01[1];
    float e2 = (float)a2[0]  - (float)b2[0];
    return e0 * e0 + e1 * e1 + e2 * e2;
#endif
}

__device__ __forceinline__ float dot2(half2v a, half2v b, float c) {
#if __has_builtin(__builtin_amdgcn_fdot2)
    return __builtin_amdgcn_fdot2(a, b, c, false);
#else
    return c + (float)a[0] * (float)b[0] + (float)a[1] * (float)b[1];
#endif
}

__device__ __forceinline__ half2v pack2(float a, float b) {
#if __has_builtin(__builtin_amdgcn_cvt_pkrtz)
    return __builtin_bit_cast(half2v, __builtin_amdgcn_cvt_pkrtz(a, b));
#else
    return half2v{(_Float16)a, (_Float16)b};
#endif
}

// pack (lo16(A), lo16(B)) / (hi16(A), hi16(B)) / (lo16(A), hi16(B)) as half2
__device__ __forceinline__ half2v pklo(unsigned A, unsigned B) {
#if __has_builtin(__builtin_amdgcn_perm)
    return __builtin_bit_cast(half2v, __builtin_amdgcn_perm(B, A, 0x05040100u));
#else
    return __builtin_bit_cast(half2v, (A & 0xffffu) | (B << 16));
#endif
}
__device__ __forceinline__ half2v pkhi(unsigned A, unsigned B) {
#if __has_builtin(__builtin_amdgcn_perm)
    return __builtin_bit_cast(half2v, __builtin_amdgcn_perm(B, A, 0x07060302u));
#else
    return __builtin_bit_cast(half2v, (A >> 16) | (B & 0xffff0000u));
#endif
}
__device__ __forceinline__ half2v pklh(unsigned A, unsigned B) {
#if __has_builtin(__builtin_amdgcn_perm)
    return __builtin_bit_cast(half2v, __builtin_amdgcn_perm(B, A, 0x07060100u));
#else
    return __builtin_bit_cast(half2v, (A & 0xffffu) | (B & 0xffff0000u));
#endif
}

// load reflect-padded pixel tile, pack RGB -> 3xfp16 in uint2
__device__ __forceinline__ void tile_load(const float* __restrict__ x, uint2* spx,
                                          int tid, int X0, int Y0) {
    for (int l = tid; l < NPIX; l += NT) {
        int rr = l / PCOLS;
        int cc = l - rr * PCOLS;
        int sy = Y0 + rr - 8;
        sy = sy < 0 ? -sy : (sy >= IMG ? 2 * IMG - 2 - sy : sy);
        int sc = X0 + cc - 14;
        sc = sc < 0 ? -sc : (sc >= IMG ? 2 * IMG - 2 - sc : sc);
        const float* p = x + ((size_t)sy * IMG + sc) * 3;
        uint2 u;
        u.x = (unsigned)__half_as_ushort(__float2half_rn(p[0])) |
              ((unsigned)__half_as_ushort(__float2half_rn(p[1])) << 16);
        u.y = (unsigned)__half_as_ushort(__float2half_rn(p[2]));  // hi 16 = 0
        spx[l] = u;
    }
}

// ---------------------------------------------------------------- stage 1
// (verbatim R13 -- measured ~2-3us)
__global__ void wavelet_hist(const float* __restrict__ x, int* __restrict__ hist) {
    int idx = blockIdx.x * 256 + threadIdx.x;
    if (idx >= HH_S * HH_S) return;
    int* hrep = hist + (blockIdx.x & (NREP - 1)) * 3 * NBINS;
    int i = (idx / HH_S) * 2;
    int j = (idx - (idx / HH_S) * HH_S) * 2;
    const float k4[4] = {-0.48296291314469025f, 0.8365163037378079f,
                         -0.2241438680420134f, -0.12940952255126037f};
    float acc0 = 0.f, acc1 = 0.f, acc2 = 0.f;
    const bool fast = (j >= 2 && j <= 511);
#pragma unroll
    for (int a = 0; a < 4; ++a) {
        int sy = 2 * i + a - 3;                       // 'symmetric' pad
        sy = sy < 0 ? -sy - 1 : (sy >= IMG ? 2 * IMG - 1 - sy : sy);
        const float* row = x + (size_t)sy * IMG * 3;
        float r0, r1, r2;
        if (fast) {
            const float* p = row + (2 * j - 3) * 3;
            float f0 = p[0], f1 = p[1], f2 = p[2], f3 = p[3];
            float f4 = p[4], f5 = p[5], f6 = p[6], f7 = p[7];
            float f8 = p[8], f9 = p[9], f10 = p[10], f11 = p[11];
            r0 = k4[0] * f0 + k4[1] * f3 + k4[2] * f6 + k4[3] * f9;
            r1 = k4[0] * f1 + k4[1] * f4 + k4[2] * f7 + k4[3] * f10;
            r2 = k4[0] * f2 + k4[1] * f5 + k4[2] * f8 + k4[3] * f11;
        } else {
            r0 = r1 = r2 = 0.f;
#pragma unroll
            for (int b = 0; b < 4; ++b) {
                int sx = 2 * j + b - 3;
                sx = sx < 0 ? -sx - 1 : (sx >= IMG ? 2 * IMG - 1 - sx : sx);
                const float* p = row + sx * 3;
                r0 += k4[b] * p[0]; r1 += k4[b] * p[1]; r2 += k4[b] * p[2];
            }
        }
        acc0 += k4[a] * r0; acc1 += k4[a] * r1; acc2 += k4[a] * r2;
    }
    int b0 = (int)(fabsf(acc0) * BIN_SCALE); b0 = b0 > NBINS - 1 ? NBINS - 1 : b0;
    int b1 = (int)(fabsf(acc1) * BIN_SCALE); b1 = b1 > NBINS - 1 ? NBINS - 1 : b1;
    int b2 = (int)(fabsf(acc2) * BIN_SCALE); b2 = b2 > NBINS - 1 ? NBINS - 1 : b2;
    atomicAdd(&hrep[b0], 1);
    atomicAdd(&hrep[NBINS + b1], 1);
    atomicAdd(&hrep[2 * NBINS + b2], 1);
}

// ---------------------------------------------------------------- stage 2
// (verbatim R13 -- one block per channel; accumulates med*MAD_INV/3 into scal[0])
__global__ void sigma_scan(const int* __restrict__ hist, float* __restrict__ scal) {
    __shared__ int   wsum[16];
    __shared__ float sres[1];
    const int t = threadIdx.x;
    const int lane = t & 63, wid = t >> 6;
    const int c = blockIdx.x;
    const int* h = hist + c * NBINS;
    int cnt[4]; int tsum = 0;
#pragma unroll
    for (int b = 0; b < 4; ++b) {
        int bin = t * 4 + b, s = 0;
#pragma unroll
        for (int r = 0; r < NREP; ++r) s += h[r * 3 * NBINS + bin];
        cnt[b] = s; tsum += s;
    }
    int incl = tsum;
#pragma unroll
    for (int o = 1; o < 64; o <<= 1) {
        int v = __shfl_up(incl, o);
        if (lane >= o) incl += v;
    }
    if (lane == 63) wsum[wid] = incl;
    __syncthreads();
    if (wid == 0) {
        int v = (lane < 16) ? wsum[lane] : 0;
        int inc = v;
#pragma unroll
        for (int o = 1; o < 16; o <<= 1) {
            int u = __shfl_up(inc, o);
            if (lane >= o) inc += u;
        }
        if (lane < 16) wsum[lane] = inc - v;
    }
    __syncthreads();
    int cum = wsum[wid] + incl - tsum;
#pragma unroll
    for (int b = 0; b < 4; ++b) {
        int nc = cum + cnt[b];
        float v = (t * 4 + b + 0.5f) * (1.0f / BIN_SCALE);
        if (cum < MED_K && nc >= MED_K) sres[0] = v;
        cum = nc;
    }
    __syncthreads();
    if (t == 0) atomicAdd(&scal[0], sres[0] * (MAD_INV / 3.0f));
}

// ---------------------------------------------------------------- main loop
// 42 iters x (A: SPLIT-pair diff^2 -> sds (contiguous b64/b32), B: horiz
// 5-tap -> shh (b128), W: quad vert 5-tap + exp2 -> swt (contiguous b128),
// C: 1x4 fdot2 accumulate (<=8B/lane)). 3 barriers/iter.
__device__ __forceinline__ void nlm_loop(float* __restrict__ out, float sigma,
                                         uint2* spx, half2v* sds, half2v* shh,
                                         half2v* swt, int tid, int X0, int Y0) {
    const float var   = 2.0f * sigma * sigma;
    const float ih2l  = LOG2E / (0.64f * sigma * sigma);   // h = 0.8*sigma

    const int c  = tid & 63;          // output col within tile
    const int rg = (tid >> 6) * 4;    // first of 4 output rows (0..60)
    float accx[4] = {0, 0, 0, 0}, accy[4] = {0, 0, 0, 0};
    float accz[4] = {0, 0, 0, 0}, accw[4] = {0, 0, 0, 0};

    __syncthreads();

    // --- register-cache center values for SPLIT-pair phase A tasks:
    // task pr: row dr = pr/40, slot j = pr-40*dr; covers sds cols j and j+40.
    half2v cA01[3], cA2[3], cB01[3], cB2[3];
    int    pba[3], sbw[3];
#pragma unroll
    for (int k = 0; k < 3; ++k) {
        int pr = (k < 2 || tid < NPTAIL) ? tid + k * NT : 0;
        int dr = pr / 40;
        int j  = pr - dr * 40;
        pba[k] = dr * PCOLS + j + 6;   // PXB(dr-8, j-8)
        sbw[k] = dr * DCOLS + j;
        PxU a; a.u = spx[pba[k]];
        PxU b; b.u = spx[pba[k] + 40];
        cA01[k] = a.h[0]; cA2[k] = a.h[1];
        cB01[k] = b.h[0]; cB2[k] = b.h[1];
    }

    const half2v B0h = H2(B0), B1h = H2(B1), B2h = H2(B2);
    const half2v G0h = H2(G0), G1h = H2(G1), G2h = H2(G2);
    const half2v ones = H2(1.0f);

    // ---- pair body: offsets o1=(oy1,ox1), o2=(oy2,ox2) packed as half2;
    // each serves BOTH +o and -o directions (dist_{-o}(p) = dist_o(p-o)).
    auto pair_body = [&](auto mtag, int oy1, int ox1, int oy2, int ox2) {
        constexpr bool MERGED = decltype(mtag)::value;
        const int d1off = oy1 * PCOLS + ox1;
        const int d2off = oy2 * PCOLS + ox2;

        // -------- phase A: split-pair diff^2 -> sds; reads contiguous b64
        // @8B/lane, writes 2x b32 @4B/lane (both conflict-free patterns)
#pragma unroll
        for (int k = 0; k < 3; ++k) {
            if (k < 2 || tid < NPTAIL) {
                PxU p0, p1, p2, p3;
                p0.u = spx[pba[k] + d1off];
                p2.u = spx[pba[k] + 40 + d1off];
                if constexpr (MERGED) {
                    p1.u = spx[pba[k] + d1off + 1];
                    p3.u = spx[pba[k] + 41 + d1off];
                } else {
                    p1.u = spx[pba[k] + d2off];
                    p3.u = spx[pba[k] + 40 + d2off];
                }
                float da0 = diff2(cA01[k], cA2[k], p0.h[0], p0.h[1]);
                float db0 = diff2(cA01[k], cA2[k], p1.h[0], p1.h[1]);
                float da1 = diff2(cB01[k], cB2[k], p2.h[0], p2.h[1]);
                float db1 = diff2(cB01[k], cB2[k], p3.h[0], p3.h[1]);
                sds[sbw[k]]      = pack2(da0, db0);
                sds[sbw[k] + 40] = pack2(da1, db1);
            }
        }
        __syncthreads();

        // -------- phase B: packed horizontal conv -> shh (1406 b128 tasks)
        {
            int row = tid / 19, g = tid - row * 19;
            int b = row * DCOLS + 4 * g;
            Q4 a, q, o;
            a.u = *(const uint4*)&sds[b];
            q.u = *(const uint4*)&sds[b + 4];
            o.h[0] = B0h * a.h[0] + B1h * a.h[1] + B2h * a.h[2] + B1h * a.h[3] + B0h * q.h[0];
            o.h[1] = B0h * a.h[1] + B1h * a.h[2] + B2h * a.h[3] + B1h * q.h[0] + B0h * q.h[1];
            o.h[2] = B0h * a.h[2] + B1h * a.h[3] + B2h * q.h[0] + B1h * q.h[1] + B0h * q.h[2];
            o.h[3] = B0h * a.h[3] + B1h * q.h[0] + B2h * q.h[1] + B1h * q.h[2] + B0h * q.h[3];
            *(uint4*)&shh[row * HCOLS + 4 * g] = o.u;
            if (tid < NB - NT) {
                int j2 = tid + NT;
                int row2 = j2 / 19, g2 = j2 - row2 * 19;
                int b2 = row2 * DCOLS + 4 * g2;
                a.u = *(const uint4*)&sds[b2];
                q.u = *(const uint4*)&sds[b2 + 4];
                o.h[0] = B0h * a.h[0] + B1h * a.h[1] + B2h * a.h[2] + B1h * a.h[3] + B0h * q.h[0];
                o.h[1] = B0h * a.h[1] + B1h * a.h[2] + B2h * a.h[3] + B1h * q.h[0] + B0h * q.h[1];
                o.h[2] = B0h * a.h[2] + B1h * a.h[3] + B2h * q.h[0] + B1h * q.h[1] + B0h * q.h[2];
                o.h[3] = B0h * a.h[3] + B1h * q.h[0] + B2h * q.h[1] + B1h * q.h[2] + B0h * q.h[3];
                *(uint4*)&shh[row2 * HCOLS + 4 * g2] = o.u;
            }
        }
        __syncthreads();

        // -------- phase W: quad-width vert conv + exp2 -> swt (contiguous
        // b128 @16B/lane = conflict-free sequential pattern)
#pragma unroll
        for (int k = 0; k < 2; ++k) {
            int t = tid + k * NT;
            if (k < 1 || t < NWQ) {
                int row = t / 19, qc = t - row * 19;
                int m = row * HCOLS + 4 * qc;        // 16B aligned (304=16*19)
                Q4 s0, s1, s2, s3, s4, o;
                s0.u = *(const uint4*)&shh[m];
                s1.u = *(const uint4*)&shh[m + HCOLS];
                s2.u = *(const uint4*)&shh[m + 2 * HCOLS];
                s3.u = *(const uint4*)&shh[m + 3 * HCOLS];
                s4.u = *(const uint4*)&shh[m + 4 * HCOLS];
#pragma unroll
                for (int h = 0; h < 4; ++h) {
                    half2v d = G0h * s0.h[h] + G1h * s1.h[h] + G2h * s2.h[h]
                             + G1h * s3.h[h] + G0h * s4.h[h];
                    o.h[h] = pack2(exp2f(fminf(var - (float)d[0], 0.f) * ih2l),
                                   exp2f(fminf(var - (float)d[1], 0.f) * ih2l));
                }
                *(uint4*)&swt[m] = o.u;
            }
        }
        __syncthreads();

        // -------- phase C: accumulate 4 directions per packed pair via
        // v_dot2_f32_f16 (weights already packed; pixel pairs packed by perm).
        // All accesses <=8B/lane. (overlaps next A — no trailing barrier)
#pragma unroll
        for (int j = 0; j < 4; ++j) {
            int r = rg + j;
            half2v wp = swt[SWB(r, c)];               // (w1, w2)
            unsigned u1, u2;
            PxU pa, pbx, pm1, pm2;
            if constexpr (MERGED) {
                int wmb = SWB(r - oy1, c - ox1);
                u1 = *(const unsigned*)&swt[wmb];
                u2 = *(const unsigned*)&swt[wmb - 1];
                int ab = PXB(r + oy1, c + ox1);
                pa.u  = spx[ab]; pbx.u = spx[ab + 1];
                int mb = PXB(r - oy1, c - ox1);
                pm1.u = spx[mb]; pm2.u = spx[mb - 1];
            } else {
                u1 = *(const unsigned*)&swt[SWB(r - oy1, c - ox1)];
                u2 = *(const unsigned*)&swt[SWB(r - oy2, c - ox2)];
                pa.u  = spx[PXB(r + oy1, c + ox1)];
                pbx.u = spx[PXB(r + oy2, c + ox2)];
                pm1.u = spx[PXB(r - oy1, c - ox1)];
                pm2.u = spx[PXB(r - oy2, c - ox2)];
            }
            half2v fm = pklh(u1, u2);                 // (f1, f2)
            accx[j] = dot2(fm, pklo(pm1.u.x, pm2.u.x),
                      dot2(wp, pklo(pa.u.x, pbx.u.x), accx[j]));
            accy[j] = dot2(fm, pkhi(pm1.u.x, pm2.u.x),
                      dot2(wp, pkhi(pa.u.x, pbx.u.x), accy[j]));
            accz[j] = dot2(fm, pklo(pm1.u.y, pm2.u.y),
                      dot2(wp, pklo(pa.u.y, pbx.u.y), accz[j]));
            accw[j] = dot2(fm, ones, dot2(wp, ones, accw[j]));
        }
    };

    // ---- 42 iterations cover 84 representative offsets x 2 directions:
    // oy=0: ox 1..6 as merged pairs (1,2),(3,4),(5,6)
#pragma unroll 1
    for (int pi = 0; pi < 3; ++pi)
        pair_body(std::integral_constant<bool, true>{}, 0, 1 + 2 * pi, 0, 2 + 2 * pi);
    // oy=1..6: ox -6..5 as 6 merged pairs per row
#pragma unroll 1
    for (int oy = 1; oy <= 6; ++oy)
#pragma unroll 1
        for (int pi = 0; pi < 6; ++pi)
            pair_body(std::integral_constant<bool, true>{}, oy, -6 + 2 * pi, oy, -5 + 2 * pi);
    // leftovers (oy,6) for oy=1..6 as 3 generic pairs
#pragma unroll 1
    for (int p = 0; p < 3; ++p)
        pair_body(std::integral_constant<bool, false>{}, 2 * p + 1, 6, 2 * p + 2, 6);

    // -------- offset (0,0): d=0 -> w=1
#pragma unroll
    for (int j = 0; j < 4; ++j) {
        PxU p; p.u = spx[PXB(rg + j, c)];
        accx[j] += (float)p.h[0][0];
        accy[j] += (float)p.h[0][1];
        accz[j] += (float)p.h[1][0];
        accw[j] += 1.f;
    }

    // -------- epilogue
#pragma unroll
    for (int j = 0; j < 4; ++j) {
        int po = ((Y0 + rg + j) * IMG + X0 + c) * 3;
        float rw = 1.f / accw[j];
        out[po + 0] = accx[j] * rw;
        out[po + 1] = accy[j] * rw;
        out[po + 2] = accz[j] * rw;
    }
}

// ---------------------------------------------------------------- stage 3
__launch_bounds__(NT, 4)
__global__ void nlm_main(const float* __restrict__ x,
                         const float* __restrict__ scal,
                         float* __restrict__ out) {
    __shared__ __align__(16) uint2  spx[NPIX];   // packed half RGB (RO in loop)
    __shared__ __align__(16) half2v sds[ND];     // diff^2 pairs
    __shared__ __align__(16) half2v shh[DROWS*HCOLS];  // horiz-conv pairs
    __shared__ __align__(16) half2v swt[WROWS*HCOLS];  // weight pairs

    const int tid = threadIdx.x;
    const int X0 = blockIdx.x * TW;
    const int Y0 = blockIdx.y * TH;

    tile_load(x, spx, tid, X0, Y0);
    const float sigma = scal[0];
    nlm_loop(out, sigma, spx, sds, shh, swt, tid, X0, Y0);
}

// ---------------------------------------------------------------- launch
extern "C" void kernel_launch(void* const* d_in, const int* in_sizes, int n_in,
                              void* d_out, int out_size, void* d_ws, size_t ws_size,
                              hipStream_t stream) {
    const float* x = (const float*)d_in[0];
    float* out = (float*)d_out;
    float* scal = (float*)d_ws;                       // [0] = sigma accumulator
    int* hist = (int*)((char*)d_ws + 64);             // NREP x 3 x 4096 ints

    // zero scal (sigma accum) + histograms in one memset
    (void)hipMemsetAsync(d_ws, 0, 64 + NREP * 3 * NBINS * sizeof(int), stream);
    wavelet_hist<<<(HH_S * HH_S + 255) / 256, 256, 0, stream>>>(x, hist);
    sigma_scan<<<3, 1024, 0, stream>>>(hist, scal);
    dim3 grid(IMG / TW, IMG / TH);                    // 16 x 16 = 256 = #CUs
    nlm_main<<<grid, NT, 0, stream>>>(x, scal, out);
}

// Round 13
// 208.539 us; speedup vs baseline: 1.0372x; 1.0181x over previous
//
#include <hip/hip_runtime.h>
#include <hip/hip_fp16.h>
#include <math.h>
#include <type_traits>

// ----------------------------------------------------------------------------
// NL-means denoise (skimage slow-mode math) + db2-wavelet sigma estimate.
// R24: RESUBMIT R20 VERBATIM (session best: nlm_main 142.4us, bench 209.5us).
//   R23 post-mortem settled the conflict attribution: fixing phase A's reads
//   left SQ_LDS_BANK_CONFLICT unchanged (4.69M vs 4.68M) -> the R19->R20
//   conflict jump came from W's quad b128 (wide-op data-volume cycles, cf.
//   GEMM ds_read_b128 showing 1.7e7), NOT A's stride. Those cycles are not
//   restriding-avoidable, and W-b128 was a net win anyway. Three consecutive
//   single-variable refinements (R21b adjacent-2x2: neutral; R22 split-W:
//   regress; R23 split-A: regress) bracket R20 as the local optimum.
//   Evidence at R20: VALUBusy 67% + LDS-issue ~25% => ~90% issue-slot
//   utilization; HBM 2% of peak; barrier-elimination / bigger tiles blocked
//   by LDS capacity (needs ~194KB vs 160KB). Compute-issue roofline for
//   this structure.
// R20: A double-width (b64 writes), W quad-width (b128).
// R19: 64x64 tile, 1024 thr, 1 block/CU (halo amortization).
// R15: phase C via v_dot2_f32_f16 + v_perm packing.
// R13: swt own buffer -> 3 barriers/iter, C overlaps next A.
// Prologue = R13 3-kernel launch (~4us; ~60us bench-kernel gap is fixed
//   harness overhead).
// ----------------------------------------------------------------------------

#define IMG   1024
#define HH_S  257
#define NBINS 4096
#define NREP  2
#define BIN_SCALE 4096.0f
#define MED_K 33025      // n=257*257=66049 odd: median = a[33024] (0-based)

#define TW 64
#define TH 64
#define NT 1024                      // threads per block
// spx: rows -8..71 (80) x cols -14..77 (92)
#define PROWS 80
#define PCOLS 92
#define NPIX (PROWS*PCOLS)           // 7360
#define PXB(r,c) (((r)+8)*PCOLS + ((c)+14))
// sds: rows -8..65 (74) x cols -8..71 (80)
#define DROWS 74
#define DCOLS 80
#define ND (DROWS*DCOLS)             // 5920
#define NPAIR (ND/2)                 // 2960 double-width A tasks (40/row)
#define NPTAIL (NPAIR - 2*NT)        // 912: k=2 partial
// shh: rows -8..65 (74) x cols -6..69 (76)
#define HCOLS 76
#define NB (DROWS*19)                // 1406 horiz-conv b128 tasks
// swt: rows -6..63 (70) x cols -6..69 (76)
#define WROWS 70
#define NWQ (WROWS*19)               // 1330 col-quad W tasks
#define SWB(r,c) (((r)+6)*HCOLS + ((c)+6))

// Gaussian patch kernel, normalized separable taps
#define G0 0.05448868454910367f
#define G1 0.24420134203151178f
#define G2 0.40261994689466440f
// horizontal pass taps pre-multiplied by 1/3 (channel mean)
#define B0 0.01816289484970122f
#define B1 0.08140044734383726f
#define B2 0.13420664896488813f

#define MAD_INV 1.4826022185056018f
#define LOG2E   1.4426950408889634f

typedef _Float16 half2v __attribute__((ext_vector_type(2)));
union PxU { uint2 u; half2v h[2]; };
union Q4  { uint4 u; half2v h[4]; };
union Q2  { uint2 u; half2v h[2]; };
#define H2(x) half2v{(_Float16)(x), (_Float16)(x)}

// ---------------------------------------------------------------- helpers
__device__ __forceinline__ float diff2(half2v a01, half2v a2, half2v b01, half2v b2) {
#if __has_builtin(__builtin_amdgcn_fdot2)
    half2v e01 = a01 - b01;
    half2v e2  = a2  - b2;
    return __builtin_amdgcn_fdot2(e01, e01,
           __builtin_amdgcn_fdot2(e2, e2, 0.f, false), false);
#else
    float e0 = (float)a01[0] - (float)b01[0];
    float e1 = (float)a01[1] - (float)b01[1];
    float e2 = (float)a2[0]  - (float)b2[0];
    return e0 * e0 + e1 * e1 + e2 * e2;
#endif
}

__device__ __forceinline__ float dot2(half2v a, half2v b, float c) {
#if __has_builtin(__builtin_amdgcn_fdot2)
    return __builtin_amdgcn_fdot2(a, b, c, false);
#else
    return c + (float)a[0] * (float)b[0] + (float)a[1] * (float)b[1];
#endif
}

__device__ __forceinline__ half2v pack2(float a, float b) {
#if __has_builtin(__builtin_amdgcn_cvt_pkrtz)
    return __builtin_bit_cast(half2v, __builtin_amdgcn_cvt_pkrtz(a, b));
#else
    return half2v{(_Float16)a, (_Float16)b};
#endif
}

// pack (lo16(A), lo16(B)) / (hi16(A), hi16(B)) / (lo16(A), hi16(B)) as half2
__device__ __forceinline__ half2v pklo(unsigned A, unsigned B) {
#if __has_builtin(__builtin_amdgcn_perm)
    return __builtin_bit_cast(half2v, __builtin_amdgcn_perm(B, A, 0x05040100u));
#else
    return __builtin_bit_cast(half2v, (A & 0xffffu) | (B << 16));
#endif
}
__device__ __forceinline__ half2v pkhi(unsigned A, unsigned B) {
#if __has_builtin(__builtin_amdgcn_perm)
    return __builtin_bit_cast(half2v, __builtin_amdgcn_perm(B, A, 0x07060302u));
#else
    return __builtin_bit_cast(half2v, (A >> 16) | (B & 0xffff0000u));
#endif
}
__device__ __forceinline__ half2v pklh(unsigned A, unsigned B) {
#if __has_builtin(__builtin_amdgcn_perm)
    return __builtin_bit_cast(half2v, __builtin_amdgcn_perm(B, A, 0x07060100u));
#else
    return __builtin_bit_cast(half2v, (A & 0xffffu) | (B & 0xffff0000u));
#endif
}

// load reflect-padded pixel tile, pack RGB -> 3xfp16 in uint2
__device__ __forceinline__ void tile_load(const float* __restrict__ x, uint2* spx,
                                          int tid, int X0, int Y0) {
    for (int l = tid; l < NPIX; l += NT) {
        int rr = l / PCOLS;
        int cc = l - rr * PCOLS;
        int sy = Y0 + rr - 8;
        sy = sy < 0 ? -sy : (sy >= IMG ? 2 * IMG - 2 - sy : sy);
        int sc = X0 + cc - 14;
        sc = sc < 0 ? -sc : (sc >= IMG ? 2 * IMG - 2 - sc : sc);
        const float* p = x + ((size_t)sy * IMG + sc) * 3;
        uint2 u;
        u.x = (unsigned)__half_as_ushort(__float2half_rn(p[0])) |
              ((unsigned)__half_as_ushort(__float2half_rn(p[1])) << 16);
        u.y = (unsigned)__half_as_ushort(__float2half_rn(p[2]));  // hi 16 = 0
        spx[l] = u;
    }
}

// ---------------------------------------------------------------- stage 1
// (verbatim R13 -- measured ~2-3us)
__global__ void wavelet_hist(const float* __restrict__ x, int* __restrict__ hist) {
    int idx = blockIdx.x * 256 + threadIdx.x;
    if (idx >= HH_S * HH_S) return;
    int* hrep = hist + (blockIdx.x & (NREP - 1)) * 3 * NBINS;
    int i = (idx / HH_S) * 2;
    int j = (idx - (idx / HH_S) * HH_S) * 2;
    const float k4[4] = {-0.48296291314469025f, 0.8365163037378079f,
                         -0.2241438680420134f, -0.12940952255126037f};
    float acc0 = 0.f, acc1 = 0.f, acc2 = 0.f;
    const bool fast = (j >= 2 && j <= 511);
#pragma unroll
    for (int a = 0; a < 4; ++a) {
        int sy = 2 * i + a - 3;                       // 'symmetric' pad
        sy = sy < 0 ? -sy - 1 : (sy >= IMG ? 2 * IMG - 1 - sy : sy);
        const float* row = x + (size_t)sy * IMG * 3;
        float r0, r1, r2;
        if (fast) {
            const float* p = row + (2 * j - 3) * 3;
            float f0 = p[0], f1 = p[1], f2 = p[2], f3 = p[3];
            float f4 = p[4], f5 = p[5], f6 = p[6], f7 = p[7];
            float f8 = p[8], f9 = p[9], f10 = p[10], f11 = p[11];
            r0 = k4[0] * f0 + k4[1] * f3 + k4[2] * f6 + k4[3] * f9;
            r1 = k4[0] * f1 + k4[1] * f4 + k4[2] * f7 + k4[3] * f10;
            r2 = k4[0] * f2 + k4[1] * f5 + k4[2] * f8 + k4[3] * f11;
        } else {
            r0 = r1 = r2 = 0.f;
#pragma unroll
            for (int b = 0; b < 4; ++b) {
                int sx = 2 * j + b - 3;
                sx = sx < 0 ? -sx - 1 : (sx >= IMG ? 2 * IMG - 1 - sx : sx);
                const float* p = row + sx * 3;
                r0 += k4[b] * p[0]; r1 += k4[b] * p[1]; r2 += k4[b] * p[2];
            }
        }
        acc0 += k4[a] * r0; acc1 += k4[a] * r1; acc2 += k4[a] * r2;
    }
    int b0 = (int)(fabsf(acc0) * BIN_SCALE); b0 = b0 > NBINS - 1 ? NBINS - 1 : b0;
    int b1 = (int)(fabsf(acc1) * BIN_SCALE); b1 = b1 > NBINS - 1 ? NBINS - 1 : b1;
    int b2 = (int)(fabsf(acc2) * BIN_SCALE); b2 = b2 > NBINS - 1 ? NBINS - 1 : b2;
    atomicAdd(&hrep[b0], 1);
    atomicAdd(&hrep[NBINS + b1], 1);
    atomicAdd(&hrep[2 * NBINS + b2], 1);
}

// ---------------------------------------------------------------- stage 2
// (verbatim R13 -- one block per channel; accumulates med*MAD_INV/3 into scal[0])
__global__ void sigma_scan(const int* __restrict__ hist, float* __restrict__ scal) {
    __shared__ int   wsum[16];
    __shared__ float sres[1];
    const int t = threadIdx.x;
    const int lane = t & 63, wid = t >> 6;
    const int c = blockIdx.x;
    const int* h = hist + c * NBINS;
    int cnt[4]; int tsum = 0;
#pragma unroll
    for (int b = 0; b < 4; ++b) {
        int bin = t * 4 + b, s = 0;
#pragma unroll
        for (int r = 0; r < NREP; ++r) s += h[r * 3 * NBINS + bin];
        cnt[b] = s; tsum += s;
    }
    int incl = tsum;
#pragma unroll
    for (int o = 1; o < 64; o <<= 1) {
        int v = __shfl_up(incl, o);
        if (lane >= o) incl += v;
    }
    if (lane == 63) wsum[wid] = incl;
    __syncthreads();
    if (wid == 0) {
        int v = (lane < 16) ? wsum[lane] : 0;
        int inc = v;
#pragma unroll
        for (int o = 1; o < 16; o <<= 1) {
            int u = __shfl_up(inc, o);
            if (lane >= o) inc += u;
        }
        if (lane < 16) wsum[lane] = inc - v;
    }
    __syncthreads();
    int cum = wsum[wid] + incl - tsum;
#pragma unroll
    for (int b = 0; b < 4; ++b) {
        int nc = cum + cnt[b];
        float v = (t * 4 + b + 0.5f) * (1.0f / BIN_SCALE);
        if (cum < MED_K && nc >= MED_K) sres[0] = v;
        cum = nc;
    }
    __syncthreads();
    if (t == 0) atomicAdd(&scal[0], sres[0] * (MAD_INV / 3.0f));
}

// ---------------------------------------------------------------- main loop
// 42 iters x (A: double-width packed diff^2 -> sds, B: horiz 5-tap -> shh,
// W: quad-width vert 5-tap + exp2 -> swt, C: fdot2 accumulate). 3 barriers.
__device__ __forceinline__ void nlm_loop(float* __restrict__ out, float sigma,
                                         uint2* spx, half2v* sds, half2v* shh,
                                         half2v* swt, int tid, int X0, int Y0) {
    const float var   = 2.0f * sigma * sigma;
    const float ih2l  = LOG2E / (0.64f * sigma * sigma);   // h = 0.8*sigma

    const int c  = tid & 63;          // output col within tile
    const int rg = (tid >> 6) * 4;    // first of 4 output rows (0..60)
    float accx[4] = {0, 0, 0, 0}, accy[4] = {0, 0, 0, 0};
    float accz[4] = {0, 0, 0, 0}, accw[4] = {0, 0, 0, 0};

    __syncthreads();

    // --- register-cache center values for double-width phase A tasks:
    // pair-task pr covers sds[2pr], sds[2pr+1] (pixels at pba, pba+1);
    // 40 pairs per row, pairs never cross rows (DCOLS=80 even).
    half2v cA01[3], cA2[3], cB01[3], cB2[3];
    int    pba[3];
#pragma unroll
    for (int k = 0; k < 3; ++k) {
        int pr = (k < 2 || tid < NPTAIL) ? tid + k * NT : 0;
        int dr = pr / 40;
        int dc = 2 * (pr - dr * 40);
        pba[k] = dr * PCOLS + dc + 6;   // PXB(dr-8, dc-8)
        PxU a; a.u = spx[pba[k]];
        PxU b; b.u = spx[pba[k] + 1];
        cA01[k] = a.h[0]; cA2[k] = a.h[1];
        cB01[k] = b.h[0]; cB2[k] = b.h[1];
    }

    const half2v B0h = H2(B0), B1h = H2(B1), B2h = H2(B2);
    const half2v G0h = H2(G0), G1h = H2(G1), G2h = H2(G2);
    const half2v ones = H2(1.0f);

    // ---- pair body: offsets o1=(oy1,ox1), o2=(oy2,ox2) packed as half2;
    // each serves BOTH +o and -o directions (dist_{-o}(p) = dist_o(p-o)).
    auto pair_body = [&](auto mtag, int oy1, int ox1, int oy2, int ox2) {
        constexpr bool MERGED = decltype(mtag)::value;
        const int d1off = oy1 * PCOLS + ox1;
        const int d2off = oy2 * PCOLS + ox2;

        // -------- phase A: double-width packed diff^2 -> sds (b64 writes)
#pragma unroll
        for (int k = 0; k < 3; ++k) {
            if (k < 2 || tid < NPTAIL) {
                PxU p0, p1, p2;
                float da0, db0, da1, db1;
                p0.u = spx[pba[k] + d1off];
                p1.u = spx[pba[k] + d1off + 1];
                if constexpr (MERGED) {
                    // reads overlap: pixels A,B vs offsets d1, d1+1
                    p2.u = spx[pba[k] + d1off + 2];
                    da0 = diff2(cA01[k], cA2[k], p0.h[0], p0.h[1]);
                    db0 = diff2(cA01[k], cA2[k], p1.h[0], p1.h[1]);
                    da1 = diff2(cB01[k], cB2[k], p1.h[0], p1.h[1]);
                    db1 = diff2(cB01[k], cB2[k], p2.h[0], p2.h[1]);
                } else {
                    PxU p3;
                    p2.u = spx[pba[k] + d2off];
                    p3.u = spx[pba[k] + d2off + 1];
                    da0 = diff2(cA01[k], cA2[k], p0.h[0], p0.h[1]);
                    db0 = diff2(cA01[k], cA2[k], p2.h[0], p2.h[1]);
                    da1 = diff2(cB01[k], cB2[k], p1.h[0], p1.h[1]);
                    db1 = diff2(cB01[k], cB2[k], p3.h[0], p3.h[1]);
                }
                Q2 w; w.h[0] = pack2(da0, db0); w.h[1] = pack2(da1, db1);
                *(uint2*)&sds[2 * tid + k * 2 * NT] = w.u;
            }
        }
        __syncthreads();

        // -------- phase B: packed horizontal conv -> shh (1406 b128 tasks)
        {
            int row = tid / 19, g = tid - row * 19;
            int b = row * DCOLS + 4 * g;
            Q4 a, q, o;
            a.u = *(const uint4*)&sds[b];
            q.u = *(const uint4*)&sds[b + 4];
            o.h[0] = B0h * a.h[0] + B1h * a.h[1] + B2h * a.h[2] + B1h * a.h[3] + B0h * q.h[0];
            o.h[1] = B0h * a.h[1] + B1h * a.h[2] + B2h * a.h[3] + B1h * q.h[0] + B0h * q.h[1];
            o.h[2] = B0h * a.h[2] + B1h * a.h[3] + B2h * q.h[0] + B1h * q.h[1] + B0h * q.h[2];
            o.h[3] = B0h * a.h[3] + B1h * q.h[0] + B2h * q.h[1] + B1h * q.h[2] + B0h * q.h[3];
            *(uint4*)&shh[row * HCOLS + 4 * g] = o.u;
            if (tid < NB - NT) {
                int j2 = tid + NT;
                int row2 = j2 / 19, g2 = j2 - row2 * 19;
                int b2 = row2 * DCOLS + 4 * g2;
                a.u = *(const uint4*)&sds[b2];
                q.u = *(const uint4*)&sds[b2 + 4];
                o.h[0] = B0h * a.h[0] + B1h * a.h[1] + B2h * a.h[2] + B1h * a.h[3] + B0h * q.h[0];
                o.h[1] = B0h * a.h[1] + B1h * a.h[2] + B2h * a.h[3] + B1h * q.h[0] + B0h * q.h[1];
                o.h[2] = B0h * a.h[2] + B1h * a.h[3] + B2h * q.h[0] + B1h * q.h[1] + B0h * q.h[2];
                o.h[3] = B0h * a.h[3] + B1h * q.h[0] + B2h * q.h[1] + B1h * q.h[2] + B0h * q.h[3];
                *(uint4*)&shh[row2 * HCOLS + 4 * g2] = o.u;
            }
        }
        __syncthreads();

        // -------- phase W: quad-width vert conv + exp2 -> swt (b128 tasks)
#pragma unroll
        for (int k = 0; k < 2; ++k) {
            int t = tid + k * NT;
            if (k < 1 || t < NWQ) {
                int row = t / 19, qc = t - row * 19;
                int m = row * HCOLS + 4 * qc;        // 16B aligned (304=16*19)
                Q4 s0, s1, s2, s3, s4, o;
                s0.u = *(const uint4*)&shh[m];
                s1.u = *(const uint4*)&shh[m + HCOLS];
                s2.u = *(const uint4*)&shh[m + 2 * HCOLS];
                s3.u = *(const uint4*)&shh[m + 3 * HCOLS];
                s4.u = *(const uint4*)&shh[m + 4 * HCOLS];
#pragma unroll
                for (int h = 0; h < 4; ++h) {
                    half2v d = G0h * s0.h[h] + G1h * s1.h[h] + G2h * s2.h[h]
                             + G1h * s3.h[h] + G0h * s4.h[h];
                    o.h[h] = pack2(exp2f(fminf(var - (float)d[0], 0.f) * ih2l),
                                   exp2f(fminf(var - (float)d[1], 0.f) * ih2l));
                }
                *(uint4*)&swt[m] = o.u;
            }
        }
        __syncthreads();

        // -------- phase C: accumulate 4 directions per packed pair via
        // v_dot2_f32_f16 (weights already packed; pixel pairs packed by perm).
        // (overlaps with next iteration's phase A — no trailing barrier)
#pragma unroll
        for (int j = 0; j < 4; ++j) {
            int r = rg + j;
            half2v wp = swt[SWB(r, c)];               // (w1, w2)
            unsigned u1, u2;
            PxU pa, pbx, pm1, pm2;
            if constexpr (MERGED) {
                int wmb = SWB(r - oy1, c - ox1);
                u1 = *(const unsigned*)&swt[wmb];
                u2 = *(const unsigned*)&swt[wmb - 1];
                int ab = PXB(r + oy1, c + ox1);
                pa.u  = spx[ab]; pbx.u = spx[ab + 1];
                int mb = PXB(r - oy1, c - ox1);
                pm1.u = spx[mb]; pm2.u = spx[mb - 1];
            } else {
                u1 = *(const unsigned*)&swt[SWB(r - oy1, c - ox1)];
                u2 = *(const unsigned*)&swt[SWB(r - oy2, c - ox2)];
                pa.u  = spx[PXB(r + oy1, c + ox1)];
                pbx.u = spx[PXB(r + oy2, c + ox2)];
                pm1.u = spx[PXB(r - oy1, c - ox1)];
                pm2.u = spx[PXB(r - oy2, c - ox2)];
            }
            half2v fm = pklh(u1, u2);                 // (f1, f2)
            accx[j] = dot2(fm, pklo(pm1.u.x, pm2.u.x),
                      dot2(wp, pklo(pa.u.x, pbx.u.x), accx[j]));
            accy[j] = dot2(fm, pkhi(pm1.u.x, pm2.u.x),
                      dot2(wp, pkhi(pa.u.x, pbx.u.x), accy[j]));
            accz[j] = dot2(fm, pklo(pm1.u.y, pm2.u.y),
                      dot2(wp, pklo(pa.u.y, pbx.u.y), accz[j]));
            accw[j] = dot2(fm, ones, dot2(wp, ones, accw[j]));
        }
    };

    // ---- 42 iterations cover 84 representative offsets x 2 directions:
    // oy=0: ox 1..6 as merged pairs (1,2),(3,4),(5,6)
#pragma unroll 1
    for (int pi = 0; pi < 3; ++pi)
        pair_body(std::integral_constant<bool, true>{}, 0, 1 + 2 * pi, 0, 2 + 2 * pi);
    // oy=1..6: ox -6..5 as 6 merged pairs per row
#pragma unroll 1
    for (int oy = 1; oy <= 6; ++oy)
#pragma unroll 1
        for (int pi = 0; pi < 6; ++pi)
            pair_body(std::integral_constant<bool, true>{}, oy, -6 + 2 * pi, oy, -5 + 2 * pi);
    // leftovers (oy,6) for oy=1..6 as 3 generic pairs
#pragma unroll 1
    for (int p = 0; p < 3; ++p)
        pair_body(std::integral_constant<bool, false>{}, 2 * p + 1, 6, 2 * p + 2, 6);

    // -------- offset (0,0): d=0 -> w=1
#pragma unroll
    for (int j = 0; j < 4; ++j) {
        PxU p; p.u = spx[PXB(rg + j, c)];
        accx[j] += (float)p.h[0][0];
        accy[j] += (float)p.h[0][1];
        accz[j] += (float)p.h[1][0];
        accw[j] += 1.f;
    }

    // -------- epilogue
#pragma unroll
    for (int j = 0; j < 4; ++j) {
        int po = ((Y0 + rg + j) * IMG + X0 + c) * 3;
        float rw = 1.f / accw[j];
        out[po + 0] = accx[j] * rw;
        out[po + 1] = accy[j] * rw;
        out[po + 2] = accz[j] * rw;
    }
}

// ---------------------------------------------------------------- stage 3
__launch_bounds__(NT, 4)
__global__ void nlm_main(const float* __restrict__ x,
                         const float* __restrict__ scal,
                         float* __restrict__ out) {
    __shared__ __align__(16) uint2  spx[NPIX];   // packed half RGB (RO in loop)
    __shared__ __align__(16) half2v sds[ND];     // diff^2 pairs
    __shared__ __align__(16) half2v shh[DROWS*HCOLS];  // horiz-conv pairs
    __shared__ __align__(16) half2v swt[WROWS*HCOLS];  // weight pairs

    const int tid = threadIdx.x;
    const int X0 = blockIdx.x * TW;
    const int Y0 = blockIdx.y * TH;

    tile_load(x, spx, tid, X0, Y0);
    const float sigma = scal[0];
    nlm_loop(out, sigma, spx, sds, shh, swt, tid, X0, Y0);
}

// ---------------------------------------------------------------- launch
extern "C" void kernel_launch(void* const* d_in, const int* in_sizes, int n_in,
                              void* d_out, int out_size, void* d_ws, size_t ws_size,
                              hipStream_t stream) {
    const float* x = (const float*)d_in[0];
    float* out = (float*)d_out;
    float* scal = (float*)d_ws;                       // [0] = sigma accumulator
    int* hist = (int*)((char*)d_ws + 64);             // NREP x 3 x 4096 ints

    // zero scal (sigma accum) + histograms in one memset
    (void)hipMemsetAsync(d_ws, 0, 64 + NREP * 3 * NBINS * sizeof(int), stream);
    wavelet_hist<<<(HH_S * HH_S + 255) / 256, 256, 0, stream>>>(x, hist);
    sigma_scan<<<3, 1024, 0, stream>>>(hist, scal);
    dim3 grid(IMG / TW, IMG / TH);                    // 16 x 16 = 256 = #CUs
    nlm_main<<<grid, NT, 0, stream>>>(x, scal, out);
}